// Round 3
// baseline (180.144 us; speedup 1.0000x reference)
//
#include <hip/hip_runtime.h>
#include <hip/hip_bf16.h>
#include <stdint.h>

#define S_LEN 2048
#define D_DIM 1024
#define P_DIM 256
#define NQ_   8192
#define M_TOT 16384  // B*S

typedef __attribute__((ext_vector_type(4))) float  f32x4;
typedef __attribute__((ext_vector_type(8))) __bf16 bf16x8;
typedef __attribute__((ext_vector_type(4))) __bf16 bf16x4;

// ---------------- Kernel 0: W [1024][256] f32 -> WT [256][1024] bf16 ----------
__global__ __launch_bounds__(1024) void wt_kernel(const float* __restrict__ W,
                                                  __bf16* __restrict__ WT) {
    __shared__ __bf16 tile[32][33];
    const int k0 = blockIdx.x * 32;
    const int n0 = blockIdx.y * 32;
    const int tx = threadIdx.x, ty = threadIdx.y;
    tile[ty][tx] = (__bf16)W[(k0 + ty) * P_DIM + (n0 + tx)];
    __syncthreads();
    WT[(n0 + ty) * D_DIM + (k0 + tx)] = tile[tx][ty];
}

// ---------------- Kernel 1: H = A @ W + b  -----------------------------------
// LDS-free MFMA GEMM, explicit 2-set register ping-pong.
// Block = 256 thr = 4 waves covers 32 rows x 256 cols; wave w -> cols [w*64,+64):
// 2 m-tiles x 4 n-tiles of mfma_f32_16x16x32_bf16. grid=512 -> 2 blk/CU, 8 waves/CU.
// __launch_bounds__(256,1): allow ~130+ VGPRs so 12 loads/set stay in flight.
// sched_barrier(0) pins issue order: prefetch(set^1) -> compute(set).
__global__ __launch_bounds__(256, 1) void gemm_kernel(const float*  __restrict__ A,
                                                      const __bf16* __restrict__ WT,
                                                      const float*  __restrict__ bias,
                                                      float*        __restrict__ H) {
    const int tid = threadIdx.x;
    const int w   = tid >> 6;
    const int l   = tid & 63;
    const int lm  = l & 15;
    const int q   = l >> 4;

    const int m0 = blockIdx.x * 32;

    const float*  pa = A  + (size_t)(m0 + lm) * D_DIM + q * 8;
    const __bf16* pb = WT + (size_t)(w * 64 + lm) * D_DIM + q * 8;

    f32x4  acc[2][4] = {};
    float4 ra[2][2][2];   // [set][m-tile][half]
    bf16x8 rb[2][4];      // [set][n-tile]

    auto prefetch = [&](int set, int k) {
        #pragma unroll
        for (int mi = 0; mi < 2; ++mi) {
            ra[set][mi][0] = *(const float4*)(pa + (size_t)mi * 16 * D_DIM + k);
            ra[set][mi][1] = *(const float4*)(pa + (size_t)mi * 16 * D_DIM + k + 4);
        }
        #pragma unroll
        for (int ni = 0; ni < 4; ++ni)
            rb[set][ni] = *(const bf16x8*)(pb + (size_t)ni * 16 * D_DIM + k);
    };

    auto compute = [&](int set) {
        bf16x8 af[2];
        #pragma unroll
        for (int mi = 0; mi < 2; ++mi) {
            af[mi][0] = (__bf16)ra[set][mi][0].x; af[mi][1] = (__bf16)ra[set][mi][0].y;
            af[mi][2] = (__bf16)ra[set][mi][0].z; af[mi][3] = (__bf16)ra[set][mi][0].w;
            af[mi][4] = (__bf16)ra[set][mi][1].x; af[mi][5] = (__bf16)ra[set][mi][1].y;
            af[mi][6] = (__bf16)ra[set][mi][1].z; af[mi][7] = (__bf16)ra[set][mi][1].w;
        }
        #pragma unroll
        for (int mi = 0; mi < 2; ++mi)
            #pragma unroll
            for (int ni = 0; ni < 4; ++ni)
                acc[mi][ni] = __builtin_amdgcn_mfma_f32_16x16x32_bf16(
                    af[mi], rb[set][ni], acc[mi][ni], 0, 0, 0);
    };

    prefetch(0, 0);
    #pragma unroll 1
    for (int k0 = 0; k0 < D_DIM - 64; k0 += 64) {
        prefetch(1, k0 + 32);
        __builtin_amdgcn_sched_barrier(0);
        compute(0);
        prefetch(0, k0 + 64);
        __builtin_amdgcn_sched_barrier(0);
        compute(1);
    }
    // peeled last iteration: chunks D-64 (set0, already prefetched) and D-32 (set1)
    prefetch(1, D_DIM - 32);
    __builtin_amdgcn_sched_barrier(0);
    compute(0);
    compute(1);

    // ---- epilogue: D layout row = q*4 + r, col = lane&15
    #pragma unroll
    for (int ni = 0; ni < 4; ++ni) {
        const int col = w * 64 + ni * 16 + lm;
        const float bv = bias[col];
        #pragma unroll
        for (int mi = 0; mi < 2; ++mi) {
            const int rbase = m0 + mi * 16 + q * 4;
            #pragma unroll
            for (int r = 0; r < 4; ++r)
                H[(size_t)(rbase + r) * P_DIM + col] = acc[mi][ni][r] + bv;
        }
    }
}

// ---------------- Kernel 2: span gather -------------------------------------
__global__ __launch_bounds__(256) void gather_kernel(const float* __restrict__ H,
                                                     const int* __restrict__ s1,
                                                     const int* __restrict__ e1,
                                                     const int* __restrict__ qb,
                                                     const int* __restrict__ s2,
                                                     const int* __restrict__ e2,
                                                     float* __restrict__ out) {
    const int qi  = blockIdx.x;
    const int t   = threadIdx.x;
    const int b   = qb[qi];
    const int set = t >> 7;
    const int rem = t & 127;
    const int half = rem >> 6;
    const int c4  = (rem & 63) << 2;

    const int s = set ? s2[qi] : s1[qi];
    const int e = set ? e2[qi] : e1[qi];

    float4 v = make_float4(0.f, 0.f, 0.f, 0.f);
    if (e >= s) {
        const int ridx = half ? e : s;
        v = *(const float4*)(H + ((size_t)b * S_LEN + ridx) * P_DIM + c4);
    }
    *(float4*)(out + (size_t)set * (NQ_ * 512) + (size_t)qi * 512 + half * 256 + c4) = v;
}

// ---------------- launch ------------------------------------------------------
extern "C" void kernel_launch(void* const* d_in, const int* in_sizes, int n_in,
                              void* d_out, int out_size, void* d_ws, size_t ws_size,
                              hipStream_t stream) {
    const float* A    = (const float*)d_in[1];
    const int*   s1   = (const int*)  d_in[2];
    const int*   e1   = (const int*)  d_in[3];
    const int*   qb   = (const int*)  d_in[4];
    const int*   s2   = (const int*)  d_in[5];
    const int*   e2   = (const int*)  d_in[6];
    const float* W    = (const float*)d_in[7];
    const float* bias = (const float*)d_in[8];
    float*       out  = (float*)d_out;

    __bf16* WT = (__bf16*)d_ws;
    float*  H  = (float*)((char*)d_ws + (1 << 20));

    wt_kernel    <<<dim3(32, 8), dim3(32, 32), 0, stream>>>(W, WT);
    gemm_kernel  <<<dim3(M_TOT / 32), dim3(256), 0, stream>>>(A, WT, bias, H);
    gather_kernel<<<dim3(NQ_), dim3(256), 0, stream>>>(H, s1, e1, qb, s2, e2, out);
}

// Round 4
// 146.276 us; speedup vs baseline: 1.2315x; 1.2315x over previous
//
#include <hip/hip_runtime.h>
#include <hip/hip_bf16.h>
#include <stdint.h>

#define S_LEN 2048
#define D_DIM 1024
#define P_DIM 256
#define NQ_   8192
#define M_TOT 16384  // B*S

#define BM 32
#define BN 256
#define BK 64

typedef __attribute__((ext_vector_type(4))) float  f32x4;
typedef __attribute__((ext_vector_type(8))) __bf16 bf16x8;
typedef __attribute__((ext_vector_type(4))) __bf16 bf16x4;

__device__ __forceinline__ void async16(const void* g, void* l) {
    __builtin_amdgcn_global_load_lds(
        (const __attribute__((address_space(1))) uint32_t*)g,
        (__attribute__((address_space(3))) uint32_t*)l, 16, 0, 0);
}

// ---------------- Kernel 0: W [1024][256] f32 -> WT [256][1024] bf16 ----------
__global__ __launch_bounds__(1024) void wt_kernel(const float* __restrict__ W,
                                                  __bf16* __restrict__ WT) {
    __shared__ __bf16 tile[32][33];
    const int k0 = blockIdx.x * 32;
    const int n0 = blockIdx.y * 32;
    const int tx = threadIdx.x, ty = threadIdx.y;
    tile[ty][tx] = (__bf16)W[(k0 + ty) * P_DIM + (n0 + tx)];
    __syncthreads();
    WT[(n0 + ty) * D_DIM + (k0 + tx)] = tile[tx][ty];
}

// ---------------- Kernel 1: H = A @ W + b  -----------------------------------
// m97-style async GEMM. BM=32,BN=256,BK=64; 256 thr = 4 waves; wave w -> cols
// [w*64,+64): 2m x 4n x 2kh = 16 MFMAs/step. B staged via global_load_lds
// width=16 (async, no VGPR cost -> ~16KB/block in flight). A loads early to
// VGPR, cvt+ds_write AFTER compute so its vmcnt wait is covered by the MFMAs.
// LDS 72KB/block -> 2 blocks/CU; alternating barriers cover each other's
// vmcnt drains (m114 overlap). Rows are 128B, chunk c of row r stored at
// position c ^ (r&7): global_load_lds lane-contiguous AND stride-1-equivalent
// bank spread for the fragment ds_read_b128s.
__global__ __launch_bounds__(256, 2) void gemm_kernel(const float*  __restrict__ A,
                                                      const __bf16* __restrict__ WT,
                                                      const float*  __restrict__ bias,
                                                      float*        __restrict__ H) {
    __shared__ __bf16 As[2][BM * BK];   //  4 KB x2
    __shared__ __bf16 Bs[2][BN * BK];   // 32 KB x2

    const int tid = threadIdx.x;
    const int w   = tid >> 6;
    const int l   = tid & 63;
    const int lm  = l & 15;
    const int q   = l >> 4;

    const int m0 = blockIdx.x * BM;

    // ---- B async staging geometry: inst j of wave w covers rows [r*8, r*8+8),
    // r = w*8+j. Lane l -> row r*8 + (l>>3), slot pos l&7 holds chunk
    // c = (l&7) ^ ((l>>3)&7)  (row&7 == (l>>3)&7 since r*8 is 8-aligned).
    const int brow_l = l >> 3;                  // row within 8-row region
    const int bc     = (l & 7) ^ (brow_l & 7);  // k-chunk this lane fetches
    const __bf16* bg0 = WT + (size_t)(w * 64 + brow_l * 1) * 0;  // (unused, clarity)

    auto stageB = [&](int buf, int k0) {
        #pragma unroll
        for (int j = 0; j < 8; ++j) {
            const int r   = w * 8 + j;
            const int row = r * 8 + brow_l;
            const __bf16* g = WT + (size_t)row * D_DIM + k0 + bc * 8;
            async16(g, &Bs[buf][r * 512]);      // r*1024 bytes
        }
    };

    // ---- A staging geometry: thread t -> row t>>3, slot pos t&7,
    // chunk c = (t&7) ^ ((t>>3)&7). 8 fp32 global -> bf16x8 LDS.
    const int arow = tid >> 3;
    const int acp  = tid & 7;
    const int ac   = acp ^ (arow & 7);
    const float* agp = A + (size_t)(m0 + arow) * D_DIM + ac * 8;

    float4 fa0, fa1;
    auto loadA = [&](int k0) {
        fa0 = *(const float4*)(agp + k0);
        fa1 = *(const float4*)(agp + k0 + 4);
    };
    auto writeA = [&](int buf) {
        bf16x8 v;
        v[0] = (__bf16)fa0.x; v[1] = (__bf16)fa0.y; v[2] = (__bf16)fa0.z; v[3] = (__bf16)fa0.w;
        v[4] = (__bf16)fa1.x; v[5] = (__bf16)fa1.y; v[6] = (__bf16)fa1.z; v[7] = (__bf16)fa1.w;
        *(bf16x8*)(&As[buf][arow * BK + acp * 8]) = v;
    };

    f32x4 acc[2][4] = {};

    auto compute = [&](int buf) {
        #pragma unroll
        for (int kh = 0; kh < 2; ++kh) {
            const int pos = ((kh * 4 + q) ^ (lm & 7)) * 8;  // swizzled chunk offset
            bf16x8 af[2], bfr[4];
            #pragma unroll
            for (int mi = 0; mi < 2; ++mi)
                af[mi] = *(const bf16x8*)(&As[buf][(mi * 16 + lm) * BK + pos]);
            #pragma unroll
            for (int ni = 0; ni < 4; ++ni)
                bfr[ni] = *(const bf16x8*)(&Bs[buf][(w * 64 + ni * 16 + lm) * BK + pos]);
            #pragma unroll
            for (int mi = 0; mi < 2; ++mi)
                #pragma unroll
                for (int ni = 0; ni < 4; ++ni)
                    acc[mi][ni] = __builtin_amdgcn_mfma_f32_16x16x32_bf16(
                        af[mi], bfr[ni], acc[mi][ni], 0, 0, 0);
        }
    };

    // ---- pipeline: 16 K-steps, buffers alternate 0,1,0,1,...
    loadA(0);
    stageB(0, 0);
    writeA(0);
    __syncthreads();

    #pragma unroll 1
    for (int p = 0; p < 7; ++p) {
        const int k1 = (2 * p + 1) * BK, k2 = (2 * p + 2) * BK;
        loadA(k1); stageB(1, k1);
        __builtin_amdgcn_sched_barrier(0);
        compute(0);
        __builtin_amdgcn_sched_barrier(0);
        writeA(1);
        __syncthreads();
        loadA(k2); stageB(0, k2);
        __builtin_amdgcn_sched_barrier(0);
        compute(1);
        __builtin_amdgcn_sched_barrier(0);
        writeA(0);
        __syncthreads();
    }
    {   // step 14 (buf 0) while staging step 15 (buf 1)
        const int k1 = 15 * BK;
        loadA(k1); stageB(1, k1);
        __builtin_amdgcn_sched_barrier(0);
        compute(0);
        __builtin_amdgcn_sched_barrier(0);
        writeA(1);
        __syncthreads();
    }
    compute(1);

    // ---- epilogue: D layout row = q*4 + r, col = lane&15
    #pragma unroll
    for (int ni = 0; ni < 4; ++ni) {
        const int col = w * 64 + ni * 16 + lm;
        const float bv = bias[col];
        #pragma unroll
        for (int mi = 0; mi < 2; ++mi) {
            const int rbase = m0 + mi * 16 + q * 4;
            #pragma unroll
            for (int r = 0; r < 4; ++r)
                H[(size_t)(rbase + r) * P_DIM + col] = acc[mi][ni][r] + bv;
        }
    }
}

// ---------------- Kernel 2: span gather -------------------------------------
__global__ __launch_bounds__(256) void gather_kernel(const float* __restrict__ H,
                                                     const int* __restrict__ s1,
                                                     const int* __restrict__ e1,
                                                     const int* __restrict__ qb,
                                                     const int* __restrict__ s2,
                                                     const int* __restrict__ e2,
                                                     float* __restrict__ out) {
    const int qi  = blockIdx.x;
    const int t   = threadIdx.x;
    const int b   = qb[qi];
    const int set = t >> 7;
    const int rem = t & 127;
    const int half = rem >> 6;
    const int c4  = (rem & 63) << 2;

    const int s = set ? s2[qi] : s1[qi];
    const int e = set ? e2[qi] : e1[qi];

    float4 v = make_float4(0.f, 0.f, 0.f, 0.f);
    if (e >= s) {
        const int ridx = half ? e : s;
        v = *(const float4*)(H + ((size_t)b * S_LEN + ridx) * P_DIM + c4);
    }
    *(float4*)(out + (size_t)set * (NQ_ * 512) + (size_t)qi * 512 + half * 256 + c4) = v;
}

// ---------------- launch ------------------------------------------------------
extern "C" void kernel_launch(void* const* d_in, const int* in_sizes, int n_in,
                              void* d_out, int out_size, void* d_ws, size_t ws_size,
                              hipStream_t stream) {
    const float* A    = (const float*)d_in[1];
    const int*   s1   = (const int*)  d_in[2];
    const int*   e1   = (const int*)  d_in[3];
    const int*   qb   = (const int*)  d_in[4];
    const int*   s2   = (const int*)  d_in[5];
    const int*   e2   = (const int*)  d_in[6];
    const float* W    = (const float*)d_in[7];
    const float* bias = (const float*)d_in[8];
    float*       out  = (float*)d_out;

    __bf16* WT = (__bf16*)d_ws;
    float*  H  = (float*)((char*)d_ws + (1 << 20));

    wt_kernel    <<<dim3(32, 8), dim3(32, 32), 0, stream>>>(W, WT);
    gemm_kernel  <<<dim3(M_TOT / BM), dim3(256), 0, stream>>>(A, WT, bias, H);
    gather_kernel<<<dim3(NQ_), dim3(256), 0, stream>>>(H, s1, e1, qb, s2, e2, out);
}